// Round 3
// baseline (285.695 us; speedup 1.0000x reference)
//
#include <hip/hip_runtime.h>
#include <stdint.h>
#include <stddef.h>

#define DIM 768

typedef short short8 __attribute__((ext_vector_type(8)));
typedef float f32x4 __attribute__((ext_vector_type(4)));

__device__ inline unsigned short f2bf_rne(float f) {
    union { float f; unsigned u; } x; x.f = f;
    unsigned r = x.u + 0x7fffu + ((x.u >> 16) & 1u);
    return (unsigned short)(r >> 16);
}

__device__ inline void gload_lds16(const void* g, void* l) {
    __builtin_amdgcn_global_load_lds((const __attribute__((address_space(1))) void*)g,
                                     (__attribute__((address_space(3))) void*)l, 16, 0, 0);
}

// Kernel 1: W [K][N] fp32 -> Bt [N][K] bf16 via LDS transpose (coalesced read AND write).
__global__ __launch_bounds__(256) void convw_kernel(
    const float* __restrict__ w, unsigned short* __restrict__ Bt)
{
    __shared__ unsigned short t[64][65];
    const int k0 = blockIdx.x * 64, n0 = blockIdx.y * 64;
    const int tid = threadIdx.x;
#pragma unroll
    for (int p = 0; p < 16; ++p) {
        int e = p * 256 + tid;
        int r = e >> 6, c = e & 63;
        t[c][r] = f2bf_rne(w[(size_t)(k0 + r) * DIM + n0 + c]);
    }
    __syncthreads();
#pragma unroll
    for (int p = 0; p < 16; ++p) {
        int e = p * 256 + tid;
        int r = e >> 6, c = e & 63;
        Bt[(size_t)(n0 + r) * DIM + k0 + c] = t[r][c];
    }
}

// Kernel 2: fused gather + GEMM + conditional select (round-0 structure) with:
//  - double-buffered LDS: gather/stage K-step t+1 while computing t (ONE barrier/step,
//    scattered-gather latency hidden behind MFMA+pack instead of drained 24x)
//  - B-tile 16B-chunk XOR swizzle (slot s of row r holds chunk s^((r>>1)&3)):
//    2-way bank alias on ds_read_b128 (free) vs 8-way at plain 64B row stride
//  - 1D grid, XCD-aware bijective swizzle, n-fastest: the 6 n-blocks of an m-tile
//    share one XCD's L2, so the gathered A rows are fetched from HBM once.
// Block = 128x128 tile, BK=32, 4 waves, 4x4 16x16x32 bf16 MFMA per wave.
// LDS = 2*16K(A fp32) + 2*8K(B bf16) + 1K = 49KB; grid 768 = 3 blocks/CU (fits).
__global__ __launch_bounds__(256) void fused_gemm_kernel(
    const int* __restrict__ token,
    const int* __restrict__ need_mapper,
    const float* __restrict__ emb,
    const unsigned short* __restrict__ Bt,   // [768][768] bf16, n-major
    const float* __restrict__ bias,
    float* __restrict__ out)                 // [M][768] fp32
{
    // XCD swizzle: gridDim.x = 768 (divisible by 8), contiguous chunk per XCD.
    const int cpx  = gridDim.x >> 3;
    const int orig = blockIdx.x;
    const int wgid = (orig & 7) * cpx + (orig >> 3);
    const int tile_m = wgid / 6;
    const int tile_n = wgid - tile_m * 6;

    __shared__ float          As[2][128 * 32];   // 2 x 16 KB, chunk-swizzled fp32
    __shared__ unsigned short Bs[2][128 * 32];   // 2 x 8 KB, chunk-swizzled bf16
    __shared__ int tok_s[128];
    __shared__ int flag_s[128];

    const int tid  = threadIdx.x;
    const int wave = tid >> 6;
    const int lane = tid & 63;
    const int quad = lane >> 4;
    const int l15  = lane & 15;
    const int wm   = wave >> 1;
    const int wn   = wave & 1;

    if (tid < 128) {
        int t = token[tile_m * 128 + tid];
        tok_s[tid]  = t;
        flag_s[tid] = need_mapper[t];
    }
    __syncthreads();

    // A staging: issue j covers rows j*32..j*32+31; thread -> row +(tid>>3), chunk slot tid&7.
    // Slot s of row r holds source chunk (s ^ (r&7))  [XOR swizzle, 16B chunks].
    const int r8 = tid >> 3;
    const int c8 = tid & 7;
    const float* pA[4];
#pragma unroll
    for (int j = 0; j < 4; ++j) {
        int r = j * 32 + r8;
        pA[j] = emb + (size_t)tok_s[r] * DIM + ((c8 ^ (r & 7)) << 2);
    }
    // B staging: issue covers 64 rows; thread -> row tid>>2 (+64 on 2nd), slot tid&3.
    // Slot s of row r holds source chunk s ^ ((r>>1)&3)  [16B chunks = 8 ushorts].
    const int rb = tid >> 2;
    const int sb = tid & 3;
    const unsigned short* pB0 = Bt + (size_t)(tile_n * 128 + rb) * DIM + ((sb ^ ((rb >> 1) & 3)) << 3);
    const unsigned short* pB1 = Bt + (size_t)(tile_n * 128 + 64 + rb) * DIM + ((sb ^ (((64 + rb) >> 1) & 3)) << 3);

#define STAGE(b, kk) do { \
    _Pragma("unroll") \
    for (int j = 0; j < 4; ++j) \
        gload_lds16(pA[j] + (kk), &As[(b)][wave * 256 + j * 1024]); \
    gload_lds16(pB0 + (kk), &Bs[(b)][wave * 512]); \
    gload_lds16(pB1 + (kk), &Bs[(b)][2048 + wave * 512]); \
} while (0)

    f32x4 acc[4][4] = {};

#define COMPUTE(b) do { \
    short8 af[4], bf[4]; \
    _Pragma("unroll") \
    for (int i = 0; i < 4; ++i) { \
        const int m = wm * 64 + i * 16 + l15; \
        const float* row = &As[(b)][m << 5]; \
        f32x4 a0 = *(const f32x4*)(row + ((((quad << 1)    ) ^ (m & 7)) << 2)); \
        f32x4 a1 = *(const f32x4*)(row + ((((quad << 1) + 1) ^ (m & 7)) << 2)); \
        unsigned u0 = __float_as_uint(a0[0]) + 0x8000u; \
        unsigned u1 = __float_as_uint(a0[1]) + 0x8000u; \
        unsigned u2 = __float_as_uint(a0[2]) + 0x8000u; \
        unsigned u3 = __float_as_uint(a0[3]) + 0x8000u; \
        unsigned u4 = __float_as_uint(a1[0]) + 0x8000u; \
        unsigned u5 = __float_as_uint(a1[1]) + 0x8000u; \
        unsigned u6 = __float_as_uint(a1[2]) + 0x8000u; \
        unsigned u7 = __float_as_uint(a1[3]) + 0x8000u; \
        union { int i4[4]; short8 s; } pk; \
        pk.i4[0] = __builtin_amdgcn_perm(u1, u0, 0x07060302); \
        pk.i4[1] = __builtin_amdgcn_perm(u3, u2, 0x07060302); \
        pk.i4[2] = __builtin_amdgcn_perm(u5, u4, 0x07060302); \
        pk.i4[3] = __builtin_amdgcn_perm(u7, u6, 0x07060302); \
        af[i] = pk.s; \
    } \
    _Pragma("unroll") \
    for (int j = 0; j < 4; ++j) { \
        const int n = wn * 64 + j * 16 + l15; \
        bf[j] = *(const short8*)(&Bs[(b)][n * 32 + ((quad ^ ((n >> 1) & 3)) << 3)]); \
    } \
    _Pragma("unroll") \
    for (int i = 0; i < 4; ++i) \
        _Pragma("unroll") \
        for (int j = 0; j < 4; ++j) \
            acc[i][j] = __builtin_amdgcn_mfma_f32_16x16x32_bf16(af[i], bf[j], acc[i][j], 0, 0, 0); \
} while (0)

    STAGE(0, 0);
    __syncthreads();            // vmcnt(0) drained: buf0 ready
    int cur = 0;
    for (int kk = 32; kk < DIM; kk += 32) {
        STAGE(cur ^ 1, kk);     // prefetch next K-step's gather while computing this one
        COMPUTE(cur);
        __syncthreads();        // next buf staged; this buf's reads complete
        cur ^= 1;
    }
    COMPUTE(cur);

    // Epilogue. C/D layout: col = lane&15, row = quad*4 + reg.
    const int colg = tile_n * 128 + wn * 64 + l15;
    float bv[4];
#pragma unroll
    for (int j = 0; j < 4; ++j) bv[j] = bias[colg + j * 16];

#pragma unroll
    for (int i = 0; i < 4; ++i) {
#pragma unroll
        for (int r = 0; r < 4; ++r) {
            const int lrow = wm * 64 + i * 16 + quad * 4 + r;
            const int gm   = tile_m * 128 + lrow;
            float* orow = out + (size_t)gm * DIM + colg;
            if (flag_s[lrow]) {
#pragma unroll
                for (int j = 0; j < 4; ++j)
                    orow[j * 16] = acc[i][j][r] + bv[j];
            } else {
                const float* erow = emb + (size_t)tok_s[lrow] * DIM + colg;
#pragma unroll
                for (int j = 0; j < 4; ++j)
                    orow[j * 16] = erow[j * 16];
            }
        }
    }
#undef STAGE
#undef COMPUTE
}

extern "C" void kernel_launch(void* const* d_in, const int* in_sizes, int n_in,
                              void* d_out, int out_size, void* d_ws, size_t ws_size,
                              hipStream_t stream)
{
    const int*   token       = (const int*)d_in[0];
    const int*   need_mapper = (const int*)d_in[1];
    const float* emb         = (const float*)d_in[2];
    const float* w           = (const float*)d_in[3];
    const float* bias        = (const float*)d_in[4];
    float* out = (float*)d_out;

    const int ntok = in_sizes[0];   // 32*512 = 16384

    unsigned short* Bt = (unsigned short*)d_ws;   // 768*768 bf16 = 1.18 MB

    convw_kernel<<<dim3(DIM / 64, DIM / 64), dim3(256), 0, stream>>>(w, Bt);
    fused_gemm_kernel<<<dim3((ntok / 128) * 6), dim3(256), 0, stream>>>(
        token, need_mapper, emb, Bt, bias, out);
}

// Round 4
// 262.815 us; speedup vs baseline: 1.0871x; 1.0871x over previous
//
#include <hip/hip_runtime.h>
#include <stdint.h>
#include <stddef.h>

#define DIM 768

typedef short short8 __attribute__((ext_vector_type(8)));
typedef float f32x4 __attribute__((ext_vector_type(4)));

__device__ inline unsigned short f2bf_rne(float f) {
    union { float f; unsigned u; } x; x.f = f;
    unsigned r = x.u + 0x7fffu + ((x.u >> 16) & 1u);
    return (unsigned short)(r >> 16);
}

__device__ inline void gload_lds16(const void* g, void* l) {
    __builtin_amdgcn_global_load_lds((const __attribute__((address_space(1))) void*)g,
                                     (__attribute__((address_space(3))) void*)l, 16, 0, 0);
}

// Kernel 1: W [K][N] fp32 -> Bt [N][K] bf16 via LDS transpose (coalesced read AND write).
__global__ __launch_bounds__(256) void convw_kernel(
    const float* __restrict__ w, unsigned short* __restrict__ Bt)
{
    __shared__ unsigned short t[64][65];
    const int k0 = blockIdx.x * 64, n0 = blockIdx.y * 64;
    const int tid = threadIdx.x;
#pragma unroll
    for (int p = 0; p < 16; ++p) {
        int e = p * 256 + tid;
        int r = e >> 6, c = e & 63;
        t[c][r] = f2bf_rne(w[(size_t)(k0 + r) * DIM + n0 + c]);
    }
    __syncthreads();
#pragma unroll
    for (int p = 0; p < 16; ++p) {
        int e = p * 256 + tid;
        int r = e >> 6, c = e & 63;
        Bt[(size_t)(n0 + r) * DIM + k0 + c] = t[r][c];
    }
}

// Kernel 2: fused gather + GEMM + conditional select.
// LATENCY-BOUND kernel (r3 counters: MfmaUtil 7.5%, HBM 12%, Occ 16%) -> the fix
// is TLP: 64x128 tile, grid = 1536 blocks = 6 resident blocks/CU (vs 3 before),
// LDS only 17 KB/block. Round-0 proven loop (single buffer, 2 barriers/step);
// 2D x-fastest grid (no XCD swizzle - regression suspect from r3).
// 4 waves; each wave = 32m x 64n via 2x4 16x16x32 bf16 MFMA.
// A gathered fp32 -> LDS with 16B-chunk XOR swizzle (s ^ (r&7)), packed to bf16
// in-register; B bf16 with 16B-chunk XOR swizzle (s ^ ((r>>1)&3)) - both
// swizzles harness-verified (r0/r3, identical absmax).
__global__ __launch_bounds__(256) void fused_gemm_kernel(
    const int* __restrict__ token,
    const int* __restrict__ need_mapper,
    const float* __restrict__ emb,
    const unsigned short* __restrict__ Bt,   // [768][768] bf16, n-major
    const float* __restrict__ bias,
    float* __restrict__ out)                 // [M][768] fp32
{
    __shared__ float          As[64 * 32];    // 8 KB, chunk-swizzled fp32
    __shared__ unsigned short Bs[128 * 32];   // 8 KB, chunk-swizzled bf16
    __shared__ int tok_s[64];
    __shared__ int flag_s[64];

    const int tid  = threadIdx.x;
    const int wave = tid >> 6;
    const int lane = tid & 63;
    const int quad = lane >> 4;
    const int l15  = lane & 15;
    const int wm   = wave >> 1;
    const int wn   = wave & 1;
    const int tile_m = blockIdx.x;
    const int tile_n = blockIdx.y;

    if (tid < 64) {
        int t = token[tile_m * 64 + tid];
        tok_s[tid]  = t;
        flag_s[tid] = need_mapper[t];
    }
    __syncthreads();

    // A staging: issue j covers rows j*32..j*32+31; thread -> row j*32+(tid>>3),
    // chunk slot tid&7. Slot s of row r holds source chunk (s ^ (r&7)).
    const int r8 = tid >> 3;
    const int c8 = tid & 7;
    const float* pA[2];
#pragma unroll
    for (int j = 0; j < 2; ++j) {
        int r = j * 32 + r8;
        pA[j] = emb + (size_t)tok_s[r] * DIM + ((c8 ^ (r & 7)) << 2);
    }
    float* lA0 = As + wave * 256;             // wave-uniform LDS base (8 rows/wave/issue)

    // B staging: issue covers 64 rows; thread -> row tid>>2 (+64 on 2nd), slot tid&3.
    // Slot s of row r holds source chunk s ^ ((r>>1)&3).
    const int rb = tid >> 2;
    const int sb = tid & 3;
    const unsigned short* pB0 = Bt + (size_t)(tile_n * 128 + rb) * DIM + ((sb ^ ((rb >> 1) & 3)) << 3);
    const unsigned short* pB1 = Bt + (size_t)(tile_n * 128 + 64 + rb) * DIM + ((sb ^ (((64 + rb) >> 1) & 3)) << 3);
    unsigned short* lB = Bs + wave * 512;

    f32x4 acc[2][4] = {};

    for (int kk = 0; kk < DIM; kk += 32) {
        __syncthreads();
        gload_lds16(pA[0] + kk, lA0);
        gload_lds16(pA[1] + kk, lA0 + 1024);
        gload_lds16(pB0 + kk, lB);
        gload_lds16(pB1 + kk, lB + 2048);
        __syncthreads();

        short8 af[2], bf[4];
#pragma unroll
        for (int i = 0; i < 2; ++i) {
            const int m = wm * 32 + i * 16 + l15;
            const float* row = As + (m << 5);
            f32x4 a0 = *(const f32x4*)(row + ((((quad << 1)    ) ^ (m & 7)) << 2));
            f32x4 a1 = *(const f32x4*)(row + ((((quad << 1) + 1) ^ (m & 7)) << 2));
            unsigned u0 = __float_as_uint(a0[0]) + 0x8000u;
            unsigned u1 = __float_as_uint(a0[1]) + 0x8000u;
            unsigned u2 = __float_as_uint(a0[2]) + 0x8000u;
            unsigned u3 = __float_as_uint(a0[3]) + 0x8000u;
            unsigned u4 = __float_as_uint(a1[0]) + 0x8000u;
            unsigned u5 = __float_as_uint(a1[1]) + 0x8000u;
            unsigned u6 = __float_as_uint(a1[2]) + 0x8000u;
            unsigned u7 = __float_as_uint(a1[3]) + 0x8000u;
            union { int i4[4]; short8 s; } pk;
            pk.i4[0] = __builtin_amdgcn_perm(u1, u0, 0x07060302);
            pk.i4[1] = __builtin_amdgcn_perm(u3, u2, 0x07060302);
            pk.i4[2] = __builtin_amdgcn_perm(u5, u4, 0x07060302);
            pk.i4[3] = __builtin_amdgcn_perm(u7, u6, 0x07060302);
            af[i] = pk.s;
        }
#pragma unroll
        for (int j = 0; j < 4; ++j) {
            const int n = wn * 64 + j * 16 + l15;
            bf[j] = *(const short8*)(Bs + n * 32 + ((quad ^ ((n >> 1) & 3)) << 3));
        }
#pragma unroll
        for (int i = 0; i < 2; ++i)
#pragma unroll
            for (int j = 0; j < 4; ++j)
                acc[i][j] = __builtin_amdgcn_mfma_f32_16x16x32_bf16(af[i], bf[j], acc[i][j], 0, 0, 0);
    }

    // Epilogue. C/D layout: col = lane&15, row = quad*4 + reg.
    const int colg = tile_n * 128 + wn * 64 + l15;
    float bv[4];
#pragma unroll
    for (int j = 0; j < 4; ++j) bv[j] = bias[colg + j * 16];

#pragma unroll
    for (int i = 0; i < 2; ++i) {
#pragma unroll
        for (int r = 0; r < 4; ++r) {
            const int lrow = wm * 32 + i * 16 + quad * 4 + r;
            const int gm   = tile_m * 64 + lrow;
            float* orow = out + (size_t)gm * DIM + colg;
            if (flag_s[lrow]) {
#pragma unroll
                for (int j = 0; j < 4; ++j)
                    orow[j * 16] = acc[i][j][r] + bv[j];
            } else {
                const float* erow = emb + (size_t)tok_s[lrow] * DIM + colg;
#pragma unroll
                for (int j = 0; j < 4; ++j)
                    orow[j * 16] = erow[j * 16];
            }
        }
    }
}

extern "C" void kernel_launch(void* const* d_in, const int* in_sizes, int n_in,
                              void* d_out, int out_size, void* d_ws, size_t ws_size,
                              hipStream_t stream)
{
    const int*   token       = (const int*)d_in[0];
    const int*   need_mapper = (const int*)d_in[1];
    const float* emb         = (const float*)d_in[2];
    const float* w           = (const float*)d_in[3];
    const float* bias        = (const float*)d_in[4];
    float* out = (float*)d_out;

    const int ntok = in_sizes[0];   // 32*512 = 16384

    unsigned short* Bt = (unsigned short*)d_ws;   // 768*768 bf16 = 1.18 MB

    convw_kernel<<<dim3(DIM / 64, DIM / 64), dim3(256), 0, stream>>>(w, Bt);
    fused_gemm_kernel<<<dim3(ntok / 64, DIM / 128), dim3(256), 0, stream>>>(
        token, need_mapper, emb, Bt, bias, out);
}

// Round 5
// 244.609 us; speedup vs baseline: 1.1680x; 1.0744x over previous
//
#include <hip/hip_runtime.h>
#include <stdint.h>
#include <stddef.h>

#define DIM 768

typedef short short8 __attribute__((ext_vector_type(8)));
typedef float f32x4 __attribute__((ext_vector_type(4)));

__device__ inline unsigned short f2bf_rne(float f) {
    union { float f; unsigned u; } x; x.f = f;
    unsigned r = x.u + 0x7fffu + ((x.u >> 16) & 1u);
    return (unsigned short)(r >> 16);
}

__device__ inline void gload_lds16(const void* g, void* l) {
    __builtin_amdgcn_global_load_lds((const __attribute__((address_space(1))) void*)g,
                                     (__attribute__((address_space(3))) void*)l, 16, 0, 0);
}

// Kernel 1: W [K][N] fp32 -> Bt [N][K] bf16 via LDS transpose (coalesced read AND write).
__global__ __launch_bounds__(256) void convw_kernel(
    const float* __restrict__ w, unsigned short* __restrict__ Bt)
{
    __shared__ unsigned short t[64][65];
    const int k0 = blockIdx.x * 64, n0 = blockIdx.y * 64;
    const int tid = threadIdx.x;
#pragma unroll
    for (int p = 0; p < 16; ++p) {
        int e = p * 256 + tid;
        int r = e >> 6, c = e & 63;
        t[c][r] = f2bf_rne(w[(size_t)(k0 + r) * DIM + n0 + c]);
    }
    __syncthreads();
#pragma unroll
    for (int p = 0; p < 16; ++p) {
        int e = p * 256 + tid;
        int r = e >> 6, c = e & 63;
        Bt[(size_t)(n0 + r) * DIM + k0 + c] = t[r][c];
    }
}

// Kernel 2: fused gather + GEMM + conditional select.
// EXACT round-0 geometry (128x128 tile, BK=32, 4 waves, 2D x-fastest grid,
// A fp32 gather -> LDS with 16B-chunk XOR swizzle, in-register bf16 pack),
// with ONE structural change: double-buffered LDS + counted s_waitcnt vmcnt(6)
// + raw s_barrier instead of __syncthreads. __syncthreads drains vmcnt(0),
// fully exposing the scattered-gather latency 24x per block (r3 counters:
// MfmaUtil 7.5%, Occ 16%, HBM 12% -> latency-bound at the barrier drain).
// Counted vmcnt lets each step's 6 gathers stay in flight across the previous
// step's compute (T3/T4 mechanism, m218: counted-vs-drain0 = +38-73%).
// Correctness: every wave waits vmcnt(6) (its own prior 6 stage loads landed)
// BEFORE barrier #1, so at barrier-exit buf[cur] is fully written by all waves.
// Barrier #2 (lgkmcnt(0)) keeps this step's LDS reads ahead of the overwrite
// of buf[cur] two steps later. sched_barrier(0) after each asm wait (rule #18).
// LDS 49 KB -> 3 blocks/CU, same residency as r0 (grid-limited: 768 blocks).
__global__ __launch_bounds__(256) void fused_gemm_kernel(
    const int* __restrict__ token,
    const int* __restrict__ need_mapper,
    const float* __restrict__ emb,
    const unsigned short* __restrict__ Bt,   // [768][768] bf16, n-major
    const float* __restrict__ bias,
    float* __restrict__ out)                 // [M][768] fp32
{
    __shared__ float          As[2][128 * 32];   // 2 x 16 KB, chunk-swizzled
    __shared__ unsigned short Bs[2][128 * 32];   // 2 x 8 KB
    __shared__ int tok_s[128];
    __shared__ int flag_s[128];

    const int tid  = threadIdx.x;
    const int wave = tid >> 6;
    const int lane = tid & 63;
    const int quad = lane >> 4;
    const int l15  = lane & 15;
    const int wm   = wave >> 1;
    const int wn   = wave & 1;
    const int tile_m = blockIdx.x;
    const int tile_n = blockIdx.y;

    if (tid < 128) {
        int t = token[tile_m * 128 + tid];
        tok_s[tid]  = t;
        flag_s[tid] = need_mapper[t];
    }
    __syncthreads();

    // A staging: issue j covers rows j*32..j*32+31; lane l -> row +(l>>3), chunk slot l&7.
    // Slot s of row r holds source chunk (s ^ (r&7))  [XOR swizzle].
    const int r8 = tid >> 3;
    const int c8 = tid & 7;
    const float* pA[4];
#pragma unroll
    for (int j = 0; j < 4; ++j) {
        int r = j * 32 + r8;
        pA[j] = emb + (size_t)tok_s[r] * DIM + ((c8 ^ (r & 7)) << 2);
    }
    // B staging: row = tid>>2 (+64 on 2nd issue), 8-ushort chunk = (tid&3)*8.
    const unsigned short* pB = Bt + (size_t)(tile_n * 128 + (tid >> 2)) * DIM + (tid & 3) * 8;

#define STAGE(b, kk) do { \
    _Pragma("unroll") \
    for (int j = 0; j < 4; ++j) \
        gload_lds16(pA[j] + (kk), &As[(b)][(wave * 8) * 32 + j * 32 * 32]); \
    gload_lds16(pB + (kk),                   &Bs[(b)][wave * 512]); \
    gload_lds16(pB + (kk) + (size_t)64 * DIM, &Bs[(b)][2048 + wave * 512]); \
} while (0)

    f32x4 acc[4][4] = {};

#define COMPUTE(b) do { \
    short8 af[4], bf[4]; \
    _Pragma("unroll") \
    for (int i = 0; i < 4; ++i) { \
        const int m = wm * 64 + i * 16 + l15; \
        const float* row = &As[(b)][m << 5]; \
        f32x4 a0 = *(const f32x4*)(row + ((((quad << 1)    ) ^ (m & 7)) << 2)); \
        f32x4 a1 = *(const f32x4*)(row + ((((quad << 1) + 1) ^ (m & 7)) << 2)); \
        unsigned u0 = __float_as_uint(a0[0]) + 0x8000u; \
        unsigned u1 = __float_as_uint(a0[1]) + 0x8000u; \
        unsigned u2 = __float_as_uint(a0[2]) + 0x8000u; \
        unsigned u3 = __float_as_uint(a0[3]) + 0x8000u; \
        unsigned u4 = __float_as_uint(a1[0]) + 0x8000u; \
        unsigned u5 = __float_as_uint(a1[1]) + 0x8000u; \
        unsigned u6 = __float_as_uint(a1[2]) + 0x8000u; \
        unsigned u7 = __float_as_uint(a1[3]) + 0x8000u; \
        union { int i4[4]; short8 s; } pk; \
        pk.i4[0] = __builtin_amdgcn_perm(u1, u0, 0x07060302); \
        pk.i4[1] = __builtin_amdgcn_perm(u3, u2, 0x07060302); \
        pk.i4[2] = __builtin_amdgcn_perm(u5, u4, 0x07060302); \
        pk.i4[3] = __builtin_amdgcn_perm(u7, u6, 0x07060302); \
        af[i] = pk.s; \
    } \
    _Pragma("unroll") \
    for (int j = 0; j < 4; ++j) \
        bf[j] = *(const short8*)(&Bs[(b)][(wn * 64 + j * 16 + l15) * 32 + quad * 8]); \
    _Pragma("unroll") \
    for (int i = 0; i < 4; ++i) \
        _Pragma("unroll") \
        for (int j = 0; j < 4; ++j) \
            acc[i][j] = __builtin_amdgcn_mfma_f32_16x16x32_bf16(af[i], bf[j], acc[i][j], 0, 0, 0); \
} while (0)

    STAGE(0, 0);                       // 6 loads in flight
    int cur = 0;
    for (int kk = 32; kk < DIM; kk += 32) {
        STAGE(cur ^ 1, kk);            // +6 -> 12 in flight
        asm volatile("s_waitcnt vmcnt(6)" ::: "memory");   // prev stage landed
        __builtin_amdgcn_sched_barrier(0);
        __builtin_amdgcn_s_barrier();  // all waves: buf[cur] fully written
        COMPUTE(cur);
        asm volatile("s_waitcnt lgkmcnt(0)" ::: "memory"); // reads of buf[cur] done
        __builtin_amdgcn_sched_barrier(0);
        __builtin_amdgcn_s_barrier();  // safe to overwrite buf[cur] next iter
        cur ^= 1;
    }
    asm volatile("s_waitcnt vmcnt(0)" ::: "memory");       // last stage landed
    __builtin_amdgcn_sched_barrier(0);
    __builtin_amdgcn_s_barrier();
    COMPUTE(cur);

    // Epilogue. C/D layout: col = lane&15, row = quad*4 + reg.
    const int colg = tile_n * 128 + wn * 64 + l15;
    float bv[4];
#pragma unroll
    for (int j = 0; j < 4; ++j) bv[j] = bias[colg + j * 16];

#pragma unroll
    for (int i = 0; i < 4; ++i) {
#pragma unroll
        for (int r = 0; r < 4; ++r) {
            const int lrow = wm * 64 + i * 16 + quad * 4 + r;
            const int gm   = tile_m * 128 + lrow;
            float* orow = out + (size_t)gm * DIM + colg;
            if (flag_s[lrow]) {
#pragma unroll
                for (int j = 0; j < 4; ++j)
                    orow[j * 16] = acc[i][j][r] + bv[j];
            } else {
                const float* erow = emb + (size_t)tok_s[lrow] * DIM + colg;
#pragma unroll
                for (int j = 0; j < 4; ++j)
                    orow[j * 16] = erow[j * 16];
            }
        }
    }
#undef STAGE
#undef COMPUTE
}

extern "C" void kernel_launch(void* const* d_in, const int* in_sizes, int n_in,
                              void* d_out, int out_size, void* d_ws, size_t ws_size,
                              hipStream_t stream)
{
    const int*   token       = (const int*)d_in[0];
    const int*   need_mapper = (const int*)d_in[1];
    const float* emb         = (const float*)d_in[2];
    const float* w           = (const float*)d_in[3];
    const float* bias        = (const float*)d_in[4];
    float* out = (float*)d_out;

    const int ntok = in_sizes[0];   // 32*512 = 16384

    unsigned short* Bt = (unsigned short*)d_ws;   // 768*768 bf16 = 1.18 MB

    convw_kernel<<<dim3(DIM / 64, DIM / 64), dim3(256), 0, stream>>>(w, Bt);
    fused_gemm_kernel<<<dim3(ntok / 128, DIM / 128), dim3(256), 0, stream>>>(
        token, need_mapper, emb, Bt, bias, out);
}